// Round 1
// baseline (351.032 us; speedup 1.0000x reference)
//
#include <hip/hip_runtime.h>
#include <math.h>

#define EPSF 1e-4f

__device__ __forceinline__ float sigmoid_clip(float x) {
    float p = 1.0f / (1.0f + expf(-x));
    return fminf(fmaxf(p, EPSF), 1.0f - EPSF);
}

// softplus(x) = log(1 + e^x), numerically stable
__device__ __forceinline__ float softplus(float x) {
    return fmaxf(x, 0.0f) + log1pf(expf(-fabsf(x)));
}

// ws layout (doubles): [0]=loss_pos [1]=loss_neg [2]=loss_other [3]=count_pos [4]=count_neg [5]=count_other

__global__ __launch_bounds__(512) void neg_loss_kernel(
    const float* __restrict__ logits, const float* __restrict__ gtprob,
    double* __restrict__ ws, int A, int D, int H, int W) {
    __shared__ float pm[1000];   // 10x10x10 halo tile of prob_max
    const int Dt = D >> 3;
    int bz = blockIdx.z;
    int dz = bz % Dt;
    int ba = bz / Dt;
    int a = ba % A;
    int b = ba / A;
    int d0 = dz * 8, h0 = blockIdx.y * 8, w0 = blockIdx.x * 8;
    size_t planeHW = (size_t)H * W;
    size_t vol = (size_t)D * planeHW;
    const float* lg = logits + ((size_t)b * 4 * A + a) * vol;  // channel = cls*A + a
    size_t clsStride = (size_t)A * vol;
    int tid = threadIdx.x;

    // Fill halo tile: prob_max = max over 4 classes of clipped sigmoid
    for (int t = tid; t < 1000; t += 512) {
        int ww = t % 10;
        int r = t / 10;
        int hh = r % 10;
        int dd = r / 10;
        int d = d0 + dd - 1, h = h0 + hh - 1, w = w0 + ww - 1;
        float v = -INFINITY;
        if ((unsigned)d < (unsigned)D && (unsigned)h < (unsigned)H && (unsigned)w < (unsigned)W) {
            size_t off = (size_t)d * planeHW + (size_t)h * W + w;
            float m0 = sigmoid_clip(lg[off]);
            float m1 = sigmoid_clip(lg[clsStride + off]);
            float m2 = sigmoid_clip(lg[2 * clsStride + off]);
            float m3 = sigmoid_clip(lg[3 * clsStride + off]);
            v = fmaxf(fmaxf(m0, m1), fmaxf(m2, m3));
        }
        pm[t] = v;
    }
    __syncthreads();

    int ww = tid & 7, hh = (tid >> 3) & 7, dd = tid >> 6;
    float pmc = pm[(dd + 1) * 100 + (hh + 1) * 10 + (ww + 1)];
    float mx = -INFINITY;
#pragma unroll
    for (int i = 0; i < 3; i++)
#pragma unroll
        for (int j = 0; j < 3; j++)
#pragma unroll
            for (int l = 0; l < 3; l++)
                mx = fmaxf(mx, pm[(dd + i) * 100 + (hh + j) * 10 + (ww + l)]);

    int d = d0 + dd, h = h0 + hh, w = w0 + ww;
    size_t off = (size_t)d * planeHW + (size_t)h * W + w;
    float gt = gtprob[((size_t)b * A + a) * vol + off];
    // negmask * max_filter * thresh_filter, w_neg = prob_max^1 * mask
    float wneg = ((gt == -1.0f) && (mx == pmc) && (pmc > EPSF)) ? pmc : 0.0f;
    float lneg = (wneg != 0.0f) ? (-logf(1.0f - pmc) * wneg) : 0.0f;

    // block reduction in double
    double lsum = (double)lneg, csum = (double)wneg;
    for (int o = 32; o > 0; o >>= 1) {
        lsum += __shfl_down(lsum, o);
        csum += __shfl_down(csum, o);
    }
    __shared__ double part[16];
    int wave = tid >> 6, lane = tid & 63;
    if (lane == 0) { part[wave] = lsum; part[wave + 8] = csum; }
    __syncthreads();
    if (tid == 0) {
        double L = 0.0, C = 0.0;
#pragma unroll
        for (int i = 0; i < 8; i++) { L += part[i]; C += part[i + 8]; }
        atomicAdd(&ws[1], L);
        atomicAdd(&ws[4], C);
    }
}

// Handles both levels in one 128-thread block: t<64 -> level0, t>=64 -> level1.
__global__ __launch_bounds__(128) void pos_loss_kernel(
    const float* __restrict__ lg0, const float* __restrict__ gt0, const int* __restrict__ c0,
    const float* __restrict__ lg1, const float* __restrict__ gt1, const int* __restrict__ c1,
    const float* __restrict__ wcls, double* __restrict__ ws) {
    const int A = 2;
    int t = threadIdx.x;
    int lvl = t >> 6, tt = t & 63;
    int b = tt >> 5, k = tt & 31;
    const float* lg = lvl ? lg1 : lg0;
    const float* gt = lvl ? gt1 : gt0;
    const int* cd = lvl ? c1 : c0;
    int D = lvl ? 32 : 64, H = lvl ? 64 : 128, W = lvl ? 64 : 128;

    __shared__ unsigned present[4];  // [lvl*2 + b] class bitmask
    if (t < 4) present[t] = 0u;
    __syncthreads();

    const int* c = cd + ((size_t)b * 32 + k) * 4;
    int a = c[0], d = c[1], h = c[2], w = c[3];
    bool valid = a > -1;
    if (!valid) { a = 0; d = 0; h = 0; w = 0; }
    size_t vol = (size_t)D * H * W;
    size_t off = ((size_t)d * H + h) * (size_t)W + w;
    float gval = gt[((size_t)b * A + a) * vol + off];
    int cls = (int)gval - 1;
    cls = cls < 0 ? 0 : (cls > 3 ? 3 : cls);
    if (valid) atomicOr(&present[lvl * 2 + b], 1u << cls);
    __syncthreads();
    unsigned pmask = present[lvl * 2 + b];

    float vm = valid ? 1.0f : 0.0f;
    const float* lgb = lg + (size_t)b * 4 * A * vol;
    size_t aoff = (size_t)a * vol + off;
    float l_t = lgb[(size_t)cls * A * vol + aoff];
    float p_t = sigmoid_clip(l_t);
    float w_pos = (1.0f - p_t) * wcls[cls] * vm;
    float loss_pos = softplus(-l_t) * w_pos;  // -log_sigmoid(l_t) * w_pos
    float pt_gate = (p_t > 0.5f) ? 1.0f : 0.0f;

    float loss_other = 0.0f, count_other = 0.0f;
#pragma unroll
    for (int cc = 0; cc < 4; cc++) {
        float l_o = lgb[(size_t)cc * A * vol + aoff];
        float p_o = sigmoid_clip(l_o);
        float wo = fmaxf(p_o - (p_t - 0.05f), 0.0f) * ((p_o > 0.5f) ? 1.0f : 0.0f) * pt_gate;
        float pres = ((pmask >> cc) & 1u) ? 1.0f : 0.0f;
        wo *= (1.0f - pres) * vm;
        loss_other += softplus(l_o) * wo;  // -log_sigmoid(-l_o)
        count_other += wo;
    }

    double v0 = (double)loss_pos, v1 = (double)w_pos, v2 = (double)loss_other, v3 = (double)count_other;
    for (int o = 32; o > 0; o >>= 1) {
        v0 += __shfl_down(v0, o);
        v1 += __shfl_down(v1, o);
        v2 += __shfl_down(v2, o);
        v3 += __shfl_down(v3, o);
    }
    __shared__ double part[8];
    int wave = t >> 6, lane = t & 63;
    if (lane == 0) {
        part[wave] = v0; part[wave + 2] = v1;
        part[wave + 4] = v2; part[wave + 6] = v3;
    }
    __syncthreads();
    if (t == 0) {
        atomicAdd(&ws[0], part[0] + part[1]);
        atomicAdd(&ws[3], part[2] + part[3]);
        atomicAdd(&ws[2], part[4] + part[5]);
        atomicAdd(&ws[5], part[6] + part[7]);
    }
}

__global__ void finalize_kernel(const double* __restrict__ ws, float* __restrict__ out) {
    int i = threadIdx.x;
    if (i < 6) out[i] = (float)ws[i];
}

extern "C" void kernel_launch(void* const* d_in, const int* in_sizes, int n_in,
                              void* d_out, int out_size, void* d_ws, size_t ws_size,
                              hipStream_t stream) {
    const float *logits0 = nullptr, *gtprob0 = nullptr, *logits1 = nullptr,
                *gtprob1 = nullptr, *wcls = nullptr;
    const int *coords0 = nullptr, *coords1 = nullptr;
    // Bind inputs by element count (robust to dict vs signature ordering).
    for (int i = 0; i < n_in; i++) {
        switch (in_sizes[i]) {
            case 16777216: logits0 = (const float*)d_in[i]; break;   // 2*8*64*128*128
            case 4194304:  gtprob0 = (const float*)d_in[i]; break;   // 2*2*64*128*128
            case 2097152:  logits1 = (const float*)d_in[i]; break;   // 2*8*32*64*64
            case 524288:   gtprob1 = (const float*)d_in[i]; break;   // 2*2*32*64*64
            case 4:        wcls    = (const float*)d_in[i]; break;
            case 256:
                if (!coords0) coords0 = (const int*)d_in[i];
                else          coords1 = (const int*)d_in[i];
                break;
        }
    }
    double* ws = (double*)d_ws;
    hipMemsetAsync(d_ws, 0, 6 * sizeof(double), stream);

    // level 0: D=64 H=128 W=128, A=2, B=2 -> grid z = (64/8)*2*2 = 32
    neg_loss_kernel<<<dim3(16, 16, 32), 512, 0, stream>>>(logits0, gtprob0, ws, 2, 64, 128, 128);
    // level 1: D=32 H=64 W=64 -> grid z = (32/8)*2*2 = 16
    neg_loss_kernel<<<dim3(8, 8, 16), 512, 0, stream>>>(logits1, gtprob1, ws, 2, 32, 64, 64);
    pos_loss_kernel<<<1, 128, 0, stream>>>(logits0, gtprob0, coords0,
                                           logits1, gtprob1, coords1, wcls, ws);
    finalize_kernel<<<1, 64, 0, stream>>>(ws, (float*)d_out);
}

// Round 2
// 173.330 us; speedup vs baseline: 2.0252x; 2.0252x over previous
//
#include <hip/hip_runtime.h>
#include <math.h>

#define EPSF 1e-4f

__device__ __forceinline__ float sigmoid_clip(float x) {
    float p = 1.0f / (1.0f + expf(-x));
    return fminf(fmaxf(p, EPSF), 1.0f - EPSF);
}

// softplus(x) = log(1 + e^x), numerically stable
__device__ __forceinline__ float softplus(float x) {
    return fmaxf(x, 0.0f) + log1pf(expf(-fabsf(x)));
}

// ws layout (doubles): [0]=loss_pos [1]=loss_neg [2]=loss_other [3]=count_pos [4]=count_neg [5]=count_other

// Tile: 8(d) x 8(h) x full-W. Block (W, TY), TY = 512/W.
// LDS halo tile pm[100][W+2]; w-halo columns are always OOB (-inf).
template <int W, int TY>
__global__ __launch_bounds__(W * TY) void neg_loss_kernel(
    const float* __restrict__ logits, const float* __restrict__ gtprob,
    double* __restrict__ ws, int A, int D, int H) {
    constexpr int LW = W + 2;
    __shared__ float pm[100 * LW];
    int tx = threadIdx.x, ty = threadIdx.y;
    int h0 = blockIdx.x * 8, d0 = blockIdx.y * 8;
    int ab = blockIdx.z;
    int a = ab % A, b = ab / A;
    size_t HW = (size_t)H * W;
    size_t vol = (size_t)D * HW;
    const float* lg = logits + ((size_t)b * 4 * A + a) * vol;  // channel = cls*A + a
    size_t cs = (size_t)A * vol;

    // Halo fill: 100 (d,h) rows, each a contiguous W-float row (coalesced).
    for (int r = ty; r < 100; r += TY) {
        int dd = r / 10, hh = r - dd * 10;
        int d = d0 + dd - 1, h = h0 + hh - 1;
        float v = -INFINITY;
        if ((unsigned)d < (unsigned)D && (unsigned)h < (unsigned)H) {
            size_t off = (size_t)d * HW + (size_t)h * W + tx;
            float m0 = sigmoid_clip(lg[off]);
            float m1 = sigmoid_clip(lg[off + cs]);
            float m2 = sigmoid_clip(lg[off + 2 * cs]);
            float m3 = sigmoid_clip(lg[off + 3 * cs]);
            v = fmaxf(fmaxf(m0, m1), fmaxf(m2, m3));
        }
        pm[r * LW + tx + 1] = v;
        if (tx < 2) pm[r * LW + tx * (W + 1)] = -INFINITY;  // c=0 and c=W+1
    }
    __syncthreads();

    double lsum = 0.0, csum = 0.0;
    const float* gtb = gtprob + ((size_t)b * A + a) * vol;
    for (int hh = ty; hh < 8; hh += TY) {
        for (int dd = 0; dd < 8; dd++) {
            float pmc = pm[((dd + 1) * 10 + hh + 1) * LW + tx + 1];
            float mx = -INFINITY;
#pragma unroll
            for (int i = 0; i < 3; i++)
#pragma unroll
                for (int j = 0; j < 3; j++)
#pragma unroll
                    for (int l = 0; l < 3; l++)
                        mx = fmaxf(mx, pm[((dd + i) * 10 + hh + j) * LW + tx + l]);
            int d = d0 + dd, h = h0 + hh;
            float gt = gtb[(size_t)d * HW + (size_t)h * W + tx];
            if (gt == -1.0f && mx == pmc && pmc > EPSF) {
                lsum += (double)(-logf(1.0f - pmc) * pmc);
                csum += (double)pmc;
            }
        }
    }

    // block reduction in double
    for (int o = 32; o > 0; o >>= 1) {
        lsum += __shfl_down(lsum, o);
        csum += __shfl_down(csum, o);
    }
    __shared__ double part[16];
    int tid = ty * W + tx;
    int wave = tid >> 6, lane = tid & 63;
    constexpr int NW = (W * TY) >> 6;
    if (lane == 0) { part[wave] = lsum; part[wave + NW] = csum; }
    __syncthreads();
    if (tid == 0) {
        double L = 0.0, C = 0.0;
#pragma unroll
        for (int i = 0; i < NW; i++) { L += part[i]; C += part[i + NW]; }
        atomicAdd(&ws[1], L);
        atomicAdd(&ws[4], C);
    }
}

// Handles both levels in one 128-thread block: t<64 -> level0, t>=64 -> level1.
__global__ __launch_bounds__(128) void pos_loss_kernel(
    const float* __restrict__ lg0, const float* __restrict__ gt0, const int* __restrict__ c0,
    const float* __restrict__ lg1, const float* __restrict__ gt1, const int* __restrict__ c1,
    const float* __restrict__ wcls, double* __restrict__ ws) {
    const int A = 2;
    int t = threadIdx.x;
    int lvl = t >> 6, tt = t & 63;
    int b = tt >> 5, k = tt & 31;
    const float* lg = lvl ? lg1 : lg0;
    const float* gt = lvl ? gt1 : gt0;
    const int* cd = lvl ? c1 : c0;
    int D = lvl ? 32 : 64, H = lvl ? 64 : 128, W = lvl ? 64 : 128;

    __shared__ unsigned present[4];  // [lvl*2 + b] class bitmask
    if (t < 4) present[t] = 0u;
    __syncthreads();

    const int* c = cd + ((size_t)b * 32 + k) * 4;
    int a = c[0], d = c[1], h = c[2], w = c[3];
    bool valid = a > -1;
    if (!valid) { a = 0; d = 0; h = 0; w = 0; }
    size_t vol = (size_t)D * H * W;
    size_t off = ((size_t)d * H + h) * (size_t)W + w;
    float gval = gt[((size_t)b * A + a) * vol + off];
    int cls = (int)gval - 1;
    cls = cls < 0 ? 0 : (cls > 3 ? 3 : cls);
    if (valid) atomicOr(&present[lvl * 2 + b], 1u << cls);
    __syncthreads();
    unsigned pmask = present[lvl * 2 + b];

    float vm = valid ? 1.0f : 0.0f;
    const float* lgb = lg + (size_t)b * 4 * A * vol;
    size_t aoff = (size_t)a * vol + off;
    float l_t = lgb[(size_t)cls * A * vol + aoff];
    float p_t = sigmoid_clip(l_t);
    float w_pos = (1.0f - p_t) * wcls[cls] * vm;
    float loss_pos = softplus(-l_t) * w_pos;  // -log_sigmoid(l_t) * w_pos
    float pt_gate = (p_t > 0.5f) ? 1.0f : 0.0f;

    float loss_other = 0.0f, count_other = 0.0f;
#pragma unroll
    for (int cc = 0; cc < 4; cc++) {
        float l_o = lgb[(size_t)cc * A * vol + aoff];
        float p_o = sigmoid_clip(l_o);
        float wo = fmaxf(p_o - (p_t - 0.05f), 0.0f) * ((p_o > 0.5f) ? 1.0f : 0.0f) * pt_gate;
        float pres = ((pmask >> cc) & 1u) ? 1.0f : 0.0f;
        wo *= (1.0f - pres) * vm;
        loss_other += softplus(l_o) * wo;  // -log_sigmoid(-l_o)
        count_other += wo;
    }

    double v0 = (double)loss_pos, v1 = (double)w_pos, v2 = (double)loss_other, v3 = (double)count_other;
    for (int o = 32; o > 0; o >>= 1) {
        v0 += __shfl_down(v0, o);
        v1 += __shfl_down(v1, o);
        v2 += __shfl_down(v2, o);
        v3 += __shfl_down(v3, o);
    }
    __shared__ double part[8];
    int wave = t >> 6, lane = t & 63;
    if (lane == 0) {
        part[wave] = v0; part[wave + 2] = v1;
        part[wave + 4] = v2; part[wave + 6] = v3;
    }
    __syncthreads();
    if (t == 0) {
        atomicAdd(&ws[0], part[0] + part[1]);
        atomicAdd(&ws[3], part[2] + part[3]);
        atomicAdd(&ws[2], part[4] + part[5]);
        atomicAdd(&ws[5], part[6] + part[7]);
    }
}

__global__ void finalize_kernel(const double* __restrict__ ws, float* __restrict__ out) {
    int i = threadIdx.x;
    if (i < 6) out[i] = (float)ws[i];
}

extern "C" void kernel_launch(void* const* d_in, const int* in_sizes, int n_in,
                              void* d_out, int out_size, void* d_ws, size_t ws_size,
                              hipStream_t stream) {
    const float *logits0 = nullptr, *gtprob0 = nullptr, *logits1 = nullptr,
                *gtprob1 = nullptr, *wcls = nullptr;
    const int *coords0 = nullptr, *coords1 = nullptr;
    // Bind inputs by element count (robust to dict vs signature ordering).
    for (int i = 0; i < n_in; i++) {
        switch (in_sizes[i]) {
            case 16777216: logits0 = (const float*)d_in[i]; break;   // 2*8*64*128*128
            case 4194304:  gtprob0 = (const float*)d_in[i]; break;   // 2*2*64*128*128
            case 2097152:  logits1 = (const float*)d_in[i]; break;   // 2*8*32*64*64
            case 524288:   gtprob1 = (const float*)d_in[i]; break;   // 2*2*32*64*64
            case 4:        wcls    = (const float*)d_in[i]; break;
            case 256:
                if (!coords0) coords0 = (const int*)d_in[i];
                else          coords1 = (const int*)d_in[i];
                break;
        }
    }
    double* ws = (double*)d_ws;
    hipMemsetAsync(d_ws, 0, 6 * sizeof(double), stream);

    // level 0: D=64 H=128 W=128, A=2, B=2. grid (H/8, D/8, A*B), block (128,4)
    neg_loss_kernel<128, 4><<<dim3(16, 8, 4), dim3(128, 4), 0, stream>>>(
        logits0, gtprob0, ws, 2, 64, 128);
    // level 1: D=32 H=64 W=64. grid (8, 4, 4), block (64,8)
    neg_loss_kernel<64, 8><<<dim3(8, 4, 4), dim3(64, 8), 0, stream>>>(
        logits1, gtprob1, ws, 2, 32, 64);
    pos_loss_kernel<<<1, 128, 0, stream>>>(logits0, gtprob0, coords0,
                                           logits1, gtprob1, coords1, wcls, ws);
    finalize_kernel<<<1, 64, 0, stream>>>(ws, (float*)d_out);
}